// Round 1
// baseline (243.525 us; speedup 1.0000x reference)
//
#include <hip/hip_runtime.h>
#include <hip/hip_bf16.h>

#define Bn  512
#define DXn 128
#define Hn  512

using bf16x8 = __attribute__((ext_vector_type(8))) short;
using f32x4  = __attribute__((ext_vector_type(4))) float;

static __device__ __forceinline__ unsigned short f2bf(float f) {
    // round-to-nearest-even f32 -> bf16 (values here are finite)
    unsigned int u = __float_as_uint(f);
    u = (u + 0x7fffu + ((u >> 16) & 1u)) >> 16;
    return (unsigned short)u;
}

// ---------------------------------------------------------------------------
// Kernel 1: hxb[i][h] = sum_d x[i,d]*W1[h,d] + b1[h]   (which==0)
//           hyv[j][h] = sum_d y[j,d]*W1[h,128+d]       (which==1)
// ---------------------------------------------------------------------------
__global__ __launch_bounds__(256) void prep_h(
    const float* __restrict__ x, const float* __restrict__ y,
    const float* __restrict__ W1, const float* __restrict__ b1,
    float* __restrict__ hxb, float* __restrict__ hyv)
{
    const int which = blockIdx.z;
    const int i0 = blockIdx.y * 16;
    const int h0 = blockIdx.x * 16;
    const float* __restrict__ src = which ? y : x;
    float* __restrict__ dst = which ? hyv : hxb;
    const int off = which ? DXn : 0;

    __shared__ float xs[16][129];
    __shared__ float ws[16][129];
    const int tx = threadIdx.x, ty = threadIdx.y;
    const int t = ty * 16 + tx;
    {
        const int base = t * 8;            // 256 threads * 8 = 2048 = 16*128
        const int r = base >> 7;
        const int c = base & 127;
        const float4 v0 = *(const float4*)(&src[(i0 + r) * DXn + c]);
        const float4 v1 = *(const float4*)(&src[(i0 + r) * DXn + c + 4]);
        xs[r][c + 0] = v0.x; xs[r][c + 1] = v0.y; xs[r][c + 2] = v0.z; xs[r][c + 3] = v0.w;
        xs[r][c + 4] = v1.x; xs[r][c + 5] = v1.y; xs[r][c + 6] = v1.z; xs[r][c + 7] = v1.w;
        const float4 w0 = *(const float4*)(&W1[(h0 + r) * (2 * DXn) + off + c]);
        const float4 w1 = *(const float4*)(&W1[(h0 + r) * (2 * DXn) + off + c + 4]);
        ws[r][c + 0] = w0.x; ws[r][c + 1] = w0.y; ws[r][c + 2] = w0.z; ws[r][c + 3] = w0.w;
        ws[r][c + 4] = w1.x; ws[r][c + 5] = w1.y; ws[r][c + 6] = w1.z; ws[r][c + 7] = w1.w;
    }
    __syncthreads();
    float acc = which ? 0.0f : b1[h0 + tx];
    #pragma unroll 8
    for (int c = 0; c < DXn; ++c)
        acc = fmaf(xs[ty][c], ws[tx][c], acc);
    dst[(i0 + ty) * Hn + (h0 + tx)] = acc;
}

// ---------------------------------------------------------------------------
// Kernel 2: W2 (f32, [512][512] row-major, [k][h]) -> bf16 fragment-ordered:
//   w2s[kf][hf][lane][8] with element = W2[kf*16 + (l&15)][hf*32 + (l>>4)*8 + j]
// so the main kernel's B-fragment load is one coalesced 16B load per lane.
// ---------------------------------------------------------------------------
__global__ __launch_bounds__(256) void prep_w2(
    const float* __restrict__ W2, unsigned short* __restrict__ w2s)
{
    const int T = blockIdx.x * 256 + threadIdx.x;   // 0 .. 32767 (32*16*64)
    const int l  = T & 63;
    const int hf = (T >> 6) & 15;
    const int kf = T >> 10;
    const int row = kf * 16 + (l & 15);
    const int col = hf * 32 + (l >> 4) * 8;
    const float* p = &W2[row * Hn + col];
    const float4 v0 = *(const float4*)p;
    const float4 v1 = *(const float4*)(p + 4);
    union { unsigned short us[8]; uint4 v; } pk;
    pk.us[0] = f2bf(v0.x); pk.us[1] = f2bf(v0.y); pk.us[2] = f2bf(v0.z); pk.us[3] = f2bf(v0.w);
    pk.us[4] = f2bf(v1.x); pk.us[5] = f2bf(v1.y); pk.us[6] = f2bf(v1.z); pk.us[7] = f2bf(v1.w);
    *(uint4*)(w2s + (size_t)T * 8) = pk.v;
}

// ---------------------------------------------------------------------------
// Kernel 3: main fused kernel. Block = (one i, 64 consecutive j's).
//   A[r][h] = relu(hxb[i][h] + hyv[j0+r][h])  staged bf16 in LDS (frag order)
//   C[r][k] = sum_h A[r][h] * W2[k][h]        (MFMA 16x16x32 bf16)
//   out[i][j0+r] = sum_k relu(C[r][k] + b2[k]) * W3[k] + b3
// 8 waves; wave w owns k in [64w, 64w+64) -> each W2 column read once/block.
// ---------------------------------------------------------------------------
__global__ __launch_bounds__(512) void critic_main(
    const float* __restrict__ hxb, const float* __restrict__ hyv,
    const unsigned short* __restrict__ w2s, const float* __restrict__ b2,
    const float* __restrict__ W3, const float* __restrict__ b3,
    float* __restrict__ out)
{
    __shared__ __align__(16) unsigned char smem[65536];
    unsigned short* a_lds = (unsigned short*)smem;  // [4 rowfrag][16 hfrag][64 lane][8]
    float* red = (float*)smem;                      // reused after MFMA: [8][64]

    const int i   = blockIdx.y;
    const int j0  = blockIdx.x * 64;
    const int tid = threadIdx.x;
    const int w   = tid >> 6;
    const int l   = tid & 63;
    const int lg  = l >> 4;     // k-group within fragment
    const int lm  = l & 15;

    // ---- stage A tile (64 rows x 512 h, bf16, fragment-ordered) ----
    {
        const int fr  = w & 3;            // row-fragment this wave fills
        const int fhb = (w >> 2) * 8;     // h-fragment range start
        const int r   = fr * 16 + lm;     // row within tile
        const float* __restrict__ hyrow = &hyv[(size_t)(j0 + r) * Hn];
        const float* __restrict__ hxrow = &hxb[(size_t)i * Hn];
        #pragma unroll
        for (int q = 0; q < 8; ++q) {
            const int fh = fhb + q;
            const int h0 = fh * 32 + lg * 8;
            const float4 a0 = *(const float4*)(hyrow + h0);
            const float4 a1 = *(const float4*)(hyrow + h0 + 4);
            const float4 x0 = *(const float4*)(hxrow + h0);
            const float4 x1 = *(const float4*)(hxrow + h0 + 4);
            union { unsigned short us[8]; uint4 v; } pk;
            pk.us[0] = f2bf(fmaxf(a0.x + x0.x, 0.f));
            pk.us[1] = f2bf(fmaxf(a0.y + x0.y, 0.f));
            pk.us[2] = f2bf(fmaxf(a0.z + x0.z, 0.f));
            pk.us[3] = f2bf(fmaxf(a0.w + x0.w, 0.f));
            pk.us[4] = f2bf(fmaxf(a1.x + x1.x, 0.f));
            pk.us[5] = f2bf(fmaxf(a1.y + x1.y, 0.f));
            pk.us[6] = f2bf(fmaxf(a1.z + x1.z, 0.f));
            pk.us[7] = f2bf(fmaxf(a1.w + x1.w, 0.f));
            *(uint4*)(a_lds + ((size_t)(fr * 16 + fh) * 64 + l) * 8) = pk.v;
        }
    }
    __syncthreads();

    // ---- GEMM: 16 h-steps, 16 MFMA each ----
    f32x4 acc[4][4] = {};
    const unsigned short* __restrict__ wbase =
        w2s + (size_t)(w * 4) * 16 * 64 * 8;   // kf = w*4 .. w*4+3

    #pragma unroll 4
    for (int s = 0; s < 16; ++s) {
        bf16x8 a[4], b[4];
        #pragma unroll
        for (int fi = 0; fi < 4; ++fi)
            a[fi] = *(const bf16x8*)(a_lds + ((size_t)(fi * 16 + s) * 64 + l) * 8);
        #pragma unroll
        for (int fj = 0; fj < 4; ++fj)
            b[fj] = *(const bf16x8*)(wbase + ((size_t)(fj * 16 + s) * 64 + l) * 8);
        #pragma unroll
        for (int fi = 0; fi < 4; ++fi)
            #pragma unroll
            for (int fj = 0; fj < 4; ++fj)
                acc[fi][fj] = __builtin_amdgcn_mfma_f32_16x16x32_bf16(
                    a[fi], b[fj], acc[fi][fj], 0, 0, 0);
    }

    // ---- epilogue: relu(C + b2)*W3, reduce over k ----
    float b2v[4], w3v[4];
    #pragma unroll
    for (int fj = 0; fj < 4; ++fj) {
        const int k = w * 64 + fj * 16 + lm;
        b2v[fj] = b2[k];
        w3v[fj] = W3[k];
    }
    float rp[4][4];
    #pragma unroll
    for (int fi = 0; fi < 4; ++fi) {
        #pragma unroll
        for (int q = 0; q < 4; ++q) {
            float ssum = 0.f;
            #pragma unroll
            for (int fj = 0; fj < 4; ++fj) {
                float c = acc[fi][fj][q] + b2v[fj];
                c = fmaxf(c, 0.f);
                ssum = fmaf(c, w3v[fj], ssum);
            }
            rp[fi][q] = ssum;
        }
    }
    // reduce across the 16-lane column group (row is constant across lm)
    #pragma unroll
    for (int m = 1; m < 16; m <<= 1) {
        #pragma unroll
        for (int fi = 0; fi < 4; ++fi)
            #pragma unroll
            for (int q = 0; q < 4; ++q)
                rp[fi][q] += __shfl_xor(rp[fi][q], m, 64);
    }

    __syncthreads();   // all waves done reading a_lds; safe to reuse as red[]
    if (lm == 0) {
        #pragma unroll
        for (int fi = 0; fi < 4; ++fi)
            #pragma unroll
            for (int q = 0; q < 4; ++q)
                red[w * 64 + fi * 16 + lg * 4 + q] = rp[fi][q];
    }
    __syncthreads();
    if (tid < 64) {
        float ssum = 0.f;
        #pragma unroll
        for (int ww = 0; ww < 8; ++ww) ssum += red[ww * 64 + tid];
        out[(size_t)i * Bn + j0 + tid] = ssum + b3[0];
    }
}

// ---------------------------------------------------------------------------
extern "C" void kernel_launch(void* const* d_in, const int* in_sizes, int n_in,
                              void* d_out, int out_size, void* d_ws, size_t ws_size,
                              hipStream_t stream) {
    const float* x  = (const float*)d_in[0];
    const float* y  = (const float*)d_in[1];
    const float* W1 = (const float*)d_in[2];
    const float* b1 = (const float*)d_in[3];
    const float* W2 = (const float*)d_in[4];
    const float* b2 = (const float*)d_in[5];
    const float* W3 = (const float*)d_in[6];
    const float* b3 = (const float*)d_in[7];
    float* out = (float*)d_out;

    char* ws = (char*)d_ws;
    float* hxb = (float*)ws;                                   // 1 MB
    float* hyv = (float*)(ws + (size_t)Bn * Hn * 4);           // 1 MB
    unsigned short* w2s = (unsigned short*)(ws + (size_t)2 * Bn * Hn * 4); // 512 KB

    prep_h<<<dim3(Hn / 16, Bn / 16, 2), dim3(16, 16), 0, stream>>>(x, y, W1, b1, hxb, hyv);
    prep_w2<<<dim3(128), dim3(256), 0, stream>>>(W2, w2s);
    critic_main<<<dim3(Bn / 64, Bn), dim3(512), 0, stream>>>(hxb, hyv, w2s, b2, W3, b3, out);
}

// Round 2
// 235.097 us; speedup vs baseline: 1.0358x; 1.0358x over previous
//
#include <hip/hip_runtime.h>
#include <hip/hip_bf16.h>

#define Bn  512
#define DXn 128
#define Hn  512

using bf16x8 = __attribute__((ext_vector_type(8))) short;
using f32x4  = __attribute__((ext_vector_type(4))) float;

// packed f32x2 -> bf16x2 (RNE); standard intrinsics so compiler emits
// v_cvt_pk_bf16_f32 (m240: hand-written asm/bit-ops are slower)
static __device__ __forceinline__ unsigned int pkbf(float lo, float hi) {
    union { __hip_bfloat162 b; unsigned int u; } cv;
    cv.b = __float22bfloat162_rn(make_float2(lo, hi));
    return cv.u;
}

// ---------------------------------------------------------------------------
// Kernel 1: hxb[i][h] = sum_d x[i,d]*W1[h,d] + b1[h]   (which==0)
//           hyv[j][h] = sum_d y[j,d]*W1[h,128+d]       (which==1)
// Register-tiled f32 GEMM: block = 32 i x 64 h, 256 threads, 8 out/thread.
// ds_read_b128 operands; ws rows at tx + u*16 so the 16-lane read pattern
// lands on 8 distinct 4-bank groups (2-way = free).
// ---------------------------------------------------------------------------
__global__ __launch_bounds__(256) void prep_h(
    const float* __restrict__ x, const float* __restrict__ y,
    const float* __restrict__ W1, const float* __restrict__ b1,
    float* __restrict__ hxb, float* __restrict__ hyv)
{
    const int which = blockIdx.z;
    const int i0 = blockIdx.y * 32;
    const int h0 = blockIdx.x * 64;
    const float* __restrict__ src = which ? y : x;
    float* __restrict__ dst = which ? hyv : hxb;
    const int off = which ? DXn : 0;

    __shared__ float xs[32][132];
    __shared__ float ws[64][132];
    const int t = threadIdx.x;
    #pragma unroll
    for (int it = 0; it < 4; ++it) {            // x tile: 32x128
        const int fi = it * 256 + t;
        const int r = fi >> 5, q = fi & 31;
        *(float4*)&xs[r][q * 4] = *(const float4*)&src[(i0 + r) * DXn + q * 4];
    }
    #pragma unroll
    for (int it = 0; it < 8; ++it) {            // W1 tile: 64x128
        const int fi = it * 256 + t;
        const int r = fi >> 5, q = fi & 31;
        *(float4*)&ws[r][q * 4] = *(const float4*)&W1[(h0 + r) * (2 * DXn) + off + q * 4];
    }
    __syncthreads();

    const int tx = t & 15;     // h: h0 + tx + u*16
    const int ty = t >> 4;     // i: i0 + ty*2 + v
    float acc[2][4];
    #pragma unroll
    for (int v = 0; v < 2; ++v)
        #pragma unroll
        for (int u = 0; u < 4; ++u)
            acc[v][u] = which ? 0.0f : b1[h0 + tx + u * 16];

    #pragma unroll 4
    for (int c4 = 0; c4 < 32; ++c4) {
        const float4 xv0 = *(const float4*)&xs[ty * 2 + 0][c4 * 4];
        const float4 xv1 = *(const float4*)&xs[ty * 2 + 1][c4 * 4];
        #pragma unroll
        for (int u = 0; u < 4; ++u) {
            const float4 wv = *(const float4*)&ws[tx + u * 16][c4 * 4];
            acc[0][u] = fmaf(xv0.x, wv.x, fmaf(xv0.y, wv.y, fmaf(xv0.z, wv.z, fmaf(xv0.w, wv.w, acc[0][u]))));
            acc[1][u] = fmaf(xv1.x, wv.x, fmaf(xv1.y, wv.y, fmaf(xv1.z, wv.z, fmaf(xv1.w, wv.w, acc[1][u]))));
        }
    }
    #pragma unroll
    for (int v = 0; v < 2; ++v)
        #pragma unroll
        for (int u = 0; u < 4; ++u)
            dst[(size_t)(i0 + ty * 2 + v) * Hn + h0 + tx + u * 16] = acc[v][u];
}

// ---------------------------------------------------------------------------
// Kernel 2: W2 (f32 [k][h] row-major) -> bf16 fragment-ordered:
//   w2s[kf][hf][lane][8], element = W2[kf*16 + (l&15)][hf*32 + (l>>4)*8 + j]
// ---------------------------------------------------------------------------
__global__ __launch_bounds__(256) void prep_w2(
    const float* __restrict__ W2, unsigned short* __restrict__ w2s)
{
    const int T = blockIdx.x * 256 + threadIdx.x;   // 0 .. 32767
    const int l  = T & 63;
    const int hf = (T >> 6) & 15;
    const int kf = T >> 10;
    const int row = kf * 16 + (l & 15);
    const int col = hf * 32 + (l >> 4) * 8;
    const float* p = &W2[row * Hn + col];
    const float4 v0 = *(const float4*)p;
    const float4 v1 = *(const float4*)(p + 4);
    uint4 pk;
    pk.x = pkbf(v0.x, v0.y);
    pk.y = pkbf(v0.z, v0.w);
    pk.z = pkbf(v1.x, v1.y);
    pk.w = pkbf(v1.z, v1.w);
    *(uint4*)(w2s + (size_t)T * 8) = pk;
}

// ---------------------------------------------------------------------------
// Kernel 3: main fused kernel. Block = (one i, 64 consecutive j's), 8 waves.
//   A[r][h] = relu(hxb[i][h] + hyv[j0+r][h])  staged bf16 in LDS (frag order)
//   C[r][k] = sum_h A[r][h] * W2[k][h]        (MFMA 16x16x32 bf16)
//   out[i][j0+r] = sum_k relu(C[r][k] + b2[k]) * W3[k] + b3
// Wave w owns k in [64w, 64w+64). B-fragments double-buffered one k-step
// ahead (L2 latency ~200cy hidden under 16-MFMA burst). VGPR kept <=128 so
// 2 blocks/CU stay resident (launch_bounds(512,4)).
// ---------------------------------------------------------------------------
__global__ __launch_bounds__(512, 4) void critic_main(
    const float* __restrict__ hxb, const float* __restrict__ hyv,
    const unsigned short* __restrict__ w2s, const float* __restrict__ b2,
    const float* __restrict__ W3, const float* __restrict__ b3,
    float* __restrict__ out)
{
    __shared__ __align__(16) unsigned char smem[65536];
    unsigned short* a_lds = (unsigned short*)smem;  // [4 rowfrag][16 hfrag][64 lane][8]
    float* red = (float*)smem;                      // reused after MFMA: [8][64]

    const int i   = blockIdx.y;
    const int j0  = blockIdx.x * 64;
    const int tid = threadIdx.x;
    const int w   = tid >> 6;
    const int l   = tid & 63;
    const int lg  = l >> 4;
    const int lm  = l & 15;

    // ---- stage A tile (64 rows x 512 h, bf16, fragment-ordered) ----
    {
        const int fr  = w & 3;
        const int fhb = (w >> 2) * 8;
        const int r   = fr * 16 + lm;
        const float* __restrict__ hyrow = &hyv[(size_t)(j0 + r) * Hn];
        const float* __restrict__ hxrow = &hxb[(size_t)i * Hn];
        #pragma unroll
        for (int q = 0; q < 8; ++q) {
            const int fh = fhb + q;
            const int h0 = fh * 32 + lg * 8;
            const float4 a0 = *(const float4*)(hyrow + h0);
            const float4 a1 = *(const float4*)(hyrow + h0 + 4);
            const float4 x0 = *(const float4*)(hxrow + h0);
            const float4 x1 = *(const float4*)(hxrow + h0 + 4);
            uint4 pk;
            pk.x = pkbf(fmaxf(a0.x + x0.x, 0.f), fmaxf(a0.y + x0.y, 0.f));
            pk.y = pkbf(fmaxf(a0.z + x0.z, 0.f), fmaxf(a0.w + x0.w, 0.f));
            pk.z = pkbf(fmaxf(a1.x + x1.x, 0.f), fmaxf(a1.y + x1.y, 0.f));
            pk.w = pkbf(fmaxf(a1.z + x1.z, 0.f), fmaxf(a1.w + x1.w, 0.f));
            *(uint4*)(a_lds + ((size_t)(fr * 16 + fh) * 64 + l) * 8) = pk;
        }
    }
    __syncthreads();

    // ---- GEMM: 16 h-steps, 16 MFMA each; B double-buffered ----
    f32x4 acc[4][4] = {};
    const unsigned short* __restrict__ wbase =
        w2s + (size_t)(w * 4) * 16 * 64 * 8;   // kf = w*4 .. w*4+3

    bf16x8 b[2][4];
    #pragma unroll
    for (int fj = 0; fj < 4; ++fj)
        b[0][fj] = *(const bf16x8*)(wbase + ((size_t)(fj * 16) * 64 + l) * 8);

    #pragma unroll
    for (int s = 0; s < 16; ++s) {
        const int cur = s & 1, nxt = cur ^ 1;
        if (s < 15) {   // prefetch next-step B (compile-time guard, full unroll)
            #pragma unroll
            for (int fj = 0; fj < 4; ++fj)
                b[nxt][fj] = *(const bf16x8*)(wbase + ((size_t)(fj * 16 + s + 1) * 64 + l) * 8);
        }
        bf16x8 a[4];
        #pragma unroll
        for (int fi = 0; fi < 4; ++fi)
            a[fi] = *(const bf16x8*)(a_lds + ((size_t)(fi * 16 + s) * 64 + l) * 8);
        #pragma unroll
        for (int fi = 0; fi < 4; ++fi)
            #pragma unroll
            for (int fj = 0; fj < 4; ++fj)
                acc[fi][fj] = __builtin_amdgcn_mfma_f32_16x16x32_bf16(
                    a[fi], b[cur][fj], acc[fi][fj], 0, 0, 0);
    }

    // ---- epilogue: relu(C + b2)*W3, reduce over k ----
    float b2v[4], w3v[4];
    #pragma unroll
    for (int fj = 0; fj < 4; ++fj) {
        const int k = w * 64 + fj * 16 + lm;
        b2v[fj] = b2[k];
        w3v[fj] = W3[k];
    }
    float rp[4][4];
    #pragma unroll
    for (int fi = 0; fi < 4; ++fi) {
        #pragma unroll
        for (int q = 0; q < 4; ++q) {
            float ssum = 0.f;
            #pragma unroll
            for (int fj = 0; fj < 4; ++fj) {
                float c = acc[fi][fj][q] + b2v[fj];
                c = fmaxf(c, 0.f);
                ssum = fmaf(c, w3v[fj], ssum);
            }
            rp[fi][q] = ssum;
        }
    }
    #pragma unroll
    for (int m = 1; m < 16; m <<= 1) {
        #pragma unroll
        for (int fi = 0; fi < 4; ++fi)
            #pragma unroll
            for (int q = 0; q < 4; ++q)
                rp[fi][q] += __shfl_xor(rp[fi][q], m, 64);
    }

    __syncthreads();   // all waves done with a_lds; safe to reuse as red[]
    if (lm == 0) {
        #pragma unroll
        for (int fi = 0; fi < 4; ++fi)
            #pragma unroll
            for (int q = 0; q < 4; ++q)
                red[w * 64 + fi * 16 + lg * 4 + q] = rp[fi][q];
    }
    __syncthreads();
    if (tid < 64) {
        float ssum = 0.f;
        #pragma unroll
        for (int ww = 0; ww < 8; ++ww) ssum += red[ww * 64 + tid];
        out[(size_t)i * Bn + j0 + tid] = ssum + b3[0];
    }
}

// ---------------------------------------------------------------------------
extern "C" void kernel_launch(void* const* d_in, const int* in_sizes, int n_in,
                              void* d_out, int out_size, void* d_ws, size_t ws_size,
                              hipStream_t stream) {
    const float* x  = (const float*)d_in[0];
    const float* y  = (const float*)d_in[1];
    const float* W1 = (const float*)d_in[2];
    const float* b1 = (const float*)d_in[3];
    const float* W2 = (const float*)d_in[4];
    const float* b2 = (const float*)d_in[5];
    const float* W3 = (const float*)d_in[6];
    const float* b3 = (const float*)d_in[7];
    float* out = (float*)d_out;

    char* ws = (char*)d_ws;
    float* hxb = (float*)ws;                                   // 1 MB
    float* hyv = (float*)(ws + (size_t)Bn * Hn * 4);           // 1 MB
    unsigned short* w2s = (unsigned short*)(ws + (size_t)2 * Bn * Hn * 4); // 512 KB

    prep_h<<<dim3(Hn / 64, Bn / 32, 2), dim3(256), 0, stream>>>(x, y, W1, b1, hxb, hyv);
    prep_w2<<<dim3(128), dim3(256), 0, stream>>>(W2, w2s);
    critic_main<<<dim3(Bn / 64, Bn), dim3(512), 0, stream>>>(hxb, hyv, w2s, b2, W3, b3, out);
}